// Round 2
// baseline (96.047 us; speedup 1.0000x reference)
//
#include <hip/hip_runtime.h>

// Problem constants (match reference setup_inputs)
#define BB 256
#define SS 2048
#define VV 100000
#define EE 128

// Kernel 1: proj[v] = dot(emb[v, :], fc_w)  for v in [0, V)
// One 64-lane wave handles 16 rows (8 pairs). Per pair: lanes 0-31 -> row r,
// lanes 32-63 -> row r+1; each lane loads one float4, so each pair-load reads
// 1024 B contiguous. All 8 loads issued back-to-back (independent vmcnt) for
// memory-level parallelism, then 8 butterfly reduces within 32-lane halves.
__global__ __launch_bounds__(256) void proj_kernel(const float* __restrict__ emb,
                                                   const float* __restrict__ fc_w,
                                                   float* __restrict__ proj) {
    const int tid  = blockIdx.x * blockDim.x + threadIdx.x;
    const int lane = threadIdx.x & 63;
    const int wave = tid >> 6;                  // global wave id
    const int sub  = lane & 31;                 // position within half-wave
    const int half = lane >> 5;                 // 0 or 1
    const int base = wave * 16 + half;          // first row for this half-wave

    const float4* __restrict__ emb4 = (const float4*)emb;
    const float4* __restrict__ w4   = (const float4*)fc_w;
    const float4 w = w4[sub];

    // 8 independent 1KB wave-loads in flight (clamp row for safety; guarded store)
    float4 a[8];
#pragma unroll
    for (int j = 0; j < 8; ++j) {
        int r = base + 2 * j;
        int rc = r < VV ? r : VV - 1;
        a[j] = emb4[(size_t)rc * (EE / 4) + sub];
    }

#pragma unroll
    for (int j = 0; j < 8; ++j) {
        float p = a[j].x * w.x + a[j].y * w.y + a[j].z * w.z + a[j].w * w.w;
#pragma unroll
        for (int off = 16; off >= 1; off >>= 1)
            p += __shfl_xor(p, off, 64);
        int r = base + 2 * j;
        if (sub == 0 && r < VV) proj[r] = p;
    }
}

// Kernel 2: out[b] = fc_b + (1/len[b]) * sum_{s<len[b]} proj[text[b,s]]
// One 256-thread block per batch row. Fully unrolled: 8 unconditional
// coalesced token loads + 8 unconditional proj gathers (text rows are fully
// allocated [B,S]; tokens < V always), masked at accumulate time. 16 loads
// outstanding per thread -> latency paid once even at 1 wave/SIMD.
__global__ __launch_bounds__(256) void pool_kernel(const int* __restrict__ text,
                                                   const int* __restrict__ lengths,
                                                   const float* __restrict__ proj,
                                                   const float* __restrict__ fc_b,
                                                   float* __restrict__ out) {
    const int b   = blockIdx.x;
    const int tid = threadIdx.x;
    const int len = lengths[b];
    const int* __restrict__ row = text + (size_t)b * SS;

    int t[8];
#pragma unroll
    for (int j = 0; j < 8; ++j)
        t[j] = row[tid + j * 256];

    float sum = 0.0f;
#pragma unroll
    for (int j = 0; j < 8; ++j) {
        float p = proj[t[j]];
        sum += (tid + j * 256 < len) ? p : 0.0f;
    }

    // wave reduce (64 lanes)
#pragma unroll
    for (int off = 32; off >= 1; off >>= 1)
        sum += __shfl_xor(sum, off, 64);

    __shared__ float ws[4];
    if ((tid & 63) == 0) ws[tid >> 6] = sum;
    __syncthreads();

    if (tid == 0) {
        float total = ws[0] + ws[1] + ws[2] + ws[3];
        out[b] = total / (float)len + fc_b[0];
    }
}

extern "C" void kernel_launch(void* const* d_in, const int* in_sizes, int n_in,
                              void* d_out, int out_size, void* d_ws, size_t ws_size,
                              hipStream_t stream) {
    const int*   text    = (const int*)d_in[0];   // [B, S]
    const int*   lengths = (const int*)d_in[1];   // [B]
    const float* emb     = (const float*)d_in[2]; // [V, E]
    const float* fc_w    = (const float*)d_in[3]; // [1, E]
    const float* fc_b    = (const float*)d_in[4]; // [1]
    float*       out     = (float*)d_out;         // [B, 1]
    float*       proj    = (float*)d_ws;          // V floats = 400 KB scratch

    // Kernel 1: 16 rows per wave -> ceil(100000/16)=6250 waves -> 1563 blocks
    const int waves  = (VV + 15) / 16;
    const int blocks = (waves + 3) / 4;
    proj_kernel<<<blocks, 256, 0, stream>>>(emb, fc_w, proj);

    // Kernel 2: one block per batch row
    pool_kernel<<<BB, 256, 0, stream>>>(text, lengths, proj, fc_b, out);
}